// Round 7
// baseline (740.689 us; speedup 1.0000x reference)
//
#include <hip/hip_runtime.h>

#define NUM_USERS 100000
#define NUM_ITEMS 50000
#define N_NODES   150000   // NUM_USERS + NUM_ITEMS
#define DIM       64
#define BATCH_N   16384
#define NPART     586      // ceil(N_NODES/256)
#define NBUCK     8        // row-slice buckets (2.4 MB CSR dest window each)
#define SC_SLICE  18750    // N_NODES / NBUCK exactly

// ---------------------------------------------------------------------------
// CSR build step 1: histogram of edge rows (int atomics, cnt is L2-resident)
// ---------------------------------------------------------------------------
__global__ __launch_bounds__(256) void lg_hist(const int* __restrict__ rows,
                                               int* __restrict__ cnt, int nnz) {
    int e = blockIdx.x * blockDim.x + threadIdx.x;
    if (e < nnz) atomicAdd(&cnt[rows[e]], 1);
}

// CSR build step 2a: per-block (256-elem) exclusive scan; block totals to part[]
__global__ __launch_bounds__(256) void lg_scan1(const int* __restrict__ cnt,
                                                int* __restrict__ ptr,
                                                int* __restrict__ part) {
    __shared__ int s[256];
    int i = blockIdx.x * 256 + threadIdx.x;
    int v = (i < N_NODES) ? cnt[i] : 0;
    s[threadIdx.x] = v;
    __syncthreads();
    #pragma unroll
    for (int off = 1; off < 256; off <<= 1) {
        int t = (threadIdx.x >= off) ? s[threadIdx.x - off] : 0;
        __syncthreads();
        s[threadIdx.x] += t;
        __syncthreads();
    }
    if (i < N_NODES) ptr[i] = s[threadIdx.x] - v;   // exclusive within block
    if (threadIdx.x == 255) part[blockIdx.x] = s[255];
}

// CSR build step 2b: single-wave exclusive scan of the 586 block totals
__global__ __launch_bounds__(64) void lg_scan2(int* __restrict__ part, int n) {
    int lane = threadIdx.x & 63;
    int run = 0;
    for (int base = 0; base < n; base += 64) {
        int i = base + lane;
        int v = (i < n) ? part[i] : 0;
        int orig = v;
        #pragma unroll
        for (int off = 1; off < 64; off <<= 1) {
            int t = __shfl_up(v, off, 64);
            if (lane >= off) v += t;
        }
        if (i < n) part[i] = run + v - orig;        // exclusive
        run += __shfl(v, 63, 64);
    }
}

// CSR build step 2c: add block offsets; also init cursor = row start
__global__ __launch_bounds__(256) void lg_scan3(int* __restrict__ ptr,
                                                const int* __restrict__ part,
                                                int* __restrict__ cur) {
    int i = blockIdx.x * 256 + threadIdx.x;
    if (i < N_NODES) {
        int p = ptr[i] + part[blockIdx.x];
        ptr[i] = p;
        cur[i] = p;
    }
}

// bucket cursors = CSR offset of each row-slice start
__global__ void lg_bcur(const int* __restrict__ ptr, int* __restrict__ bcur) {
    int t = threadIdx.x;
    if (t < NBUCK) bcur[t] = ptr[t * SC_SLICE];
}

// ---------------------------------------------------------------------------
// Scatter phase A: bucket edges by row-slice. LDS-aggregated cursor
// reservation (8 global atomics per block, not per edge); staged writes land
// in 8 rolling windows = near-sequential. Staging lives in the x1 buffer
// (unused until SpMM layer 1).
// ---------------------------------------------------------------------------
__global__ __launch_bounds__(256) void lg_bucket(const int* __restrict__ rows,
                           const int* __restrict__ cols,
                           const float* __restrict__ vals,
                           int* __restrict__ bcur,
                           int* __restrict__ brow, int2* __restrict__ bcv, int nnz) {
    __shared__ int hist[NBUCK], base[NBUCK], off[NBUCK];
    if (threadIdx.x < NBUCK) { hist[threadIdx.x] = 0; off[threadIdx.x] = 0; }
    __syncthreads();
    int e = blockIdx.x * 256 + threadIdx.x;
    int r = 0, b = -1;
    if (e < nnz) { r = rows[e]; b = r / SC_SLICE; atomicAdd(&hist[b], 1); }
    __syncthreads();
    if (threadIdx.x < NBUCK && hist[threadIdx.x] > 0)
        base[threadIdx.x] = atomicAdd(&bcur[threadIdx.x], hist[threadIdx.x]);
    __syncthreads();
    if (b >= 0) {
        int rank = atomicAdd(&off[b], 1);
        int pos  = base[b] + rank;
        brow[pos] = r;
        bcv[pos]  = make_int2(cols[e], __float_as_int(vals[e]));
    }
}

// ---------------------------------------------------------------------------
// Scatter phase B (one launch per bucket): staged reads are sequential; the
// destination is one contiguous 2.4 MB CSR slice -> per-XCD-L2-resident,
// each dirty line written back once (kills write amplification).
// ---------------------------------------------------------------------------
__global__ __launch_bounds__(256) void lg_scatter2(const int* __restrict__ brow,
                           const int2* __restrict__ bcv,
                           const int* __restrict__ ptr, int* __restrict__ cur,
                           int2* __restrict__ edges, int b, int nnz) {
    int lo = __builtin_amdgcn_readfirstlane(ptr[b * SC_SLICE]);
    int hi = (b == NBUCK - 1) ? nnz
             : __builtin_amdgcn_readfirstlane(ptr[(b + 1) * SC_SLICE]);
    int i = lo + blockIdx.x * 256 + threadIdx.x;
    if (i >= hi) return;
    int r = brow[i];
    int pos = atomicAdd(&cur[r], 1);
    edges[pos] = bcv[i];
}

// ---------------------------------------------------------------------------
// Row-parallel SpMM: one wave per row, lane = dim. No atomics, no shuffles.
// Gathers select base pointer per edge: layer 1 reads user_emb/item_emb
// directly (xi pre-offset by -NUM_USERS*DIM); layers 2/3 pass xu == xi so the
// select is a no-op. Unroll 8, 4 accumulators -> 8 gathers in flight.
// ---------------------------------------------------------------------------
__global__ __launch_bounds__(256) void lg_spmm(const int* __restrict__ ptr,
                            const int* __restrict__ cnt,
                            const int2* __restrict__ edges,
                            const float* __restrict__ xu,
                            const float* __restrict__ xi,
                            float* __restrict__ yout) {
    int r    = blockIdx.x * 4 + (threadIdx.x >> 6);
    int lane = threadIdx.x & 63;
    if (r >= N_NODES) return;
    int start = __builtin_amdgcn_readfirstlane(ptr[r]);   // SGPR: scalar addressing
    int len   = __builtin_amdgcn_readfirstlane(cnt[r]);
    const int2* __restrict__ ep = edges + start;
    float s0 = 0.0f, s1 = 0.0f, s2 = 0.0f, s3 = 0.0f;
    int j = 0;
    for (; j + 8 <= len; j += 8) {
        int2 m0 = ep[j];     int2 m1 = ep[j + 1];
        int2 m2 = ep[j + 2]; int2 m3 = ep[j + 3];
        int2 m4 = ep[j + 4]; int2 m5 = ep[j + 5];
        int2 m6 = ep[j + 6]; int2 m7 = ep[j + 7];
        const float* b0 = (m0.x < NUM_USERS) ? xu : xi;
        const float* b1 = (m1.x < NUM_USERS) ? xu : xi;
        const float* b2 = (m2.x < NUM_USERS) ? xu : xi;
        const float* b3 = (m3.x < NUM_USERS) ? xu : xi;
        const float* b4 = (m4.x < NUM_USERS) ? xu : xi;
        const float* b5 = (m5.x < NUM_USERS) ? xu : xi;
        const float* b6 = (m6.x < NUM_USERS) ? xu : xi;
        const float* b7 = (m7.x < NUM_USERS) ? xu : xi;
        s0 += __int_as_float(m0.y) * b0[(m0.x << 6) + lane];
        s1 += __int_as_float(m1.y) * b1[(m1.x << 6) + lane];
        s2 += __int_as_float(m2.y) * b2[(m2.x << 6) + lane];
        s3 += __int_as_float(m3.y) * b3[(m3.x << 6) + lane];
        s0 += __int_as_float(m4.y) * b4[(m4.x << 6) + lane];
        s1 += __int_as_float(m5.y) * b5[(m5.x << 6) + lane];
        s2 += __int_as_float(m6.y) * b6[(m6.x << 6) + lane];
        s3 += __int_as_float(m7.y) * b7[(m7.x << 6) + lane];
    }
    for (; j < len; ++j) {
        int2 m = ep[j];
        const float* b = (m.x < NUM_USERS) ? xu : xi;
        s0 += __int_as_float(m.y) * b[(m.x << 6) + lane];
    }
    float sum = (s0 + s1) + (s2 + s3);
    yout[(r << 6) + lane] = sum;
}

// ---------------------------------------------------------------------------
// preds[b] = dot(acc[u], acc[t]) / 16 with acc formed in-register from the
// 4 contributions (emb + x1 + x2 + x3) — full acc array never materialized.
// ---------------------------------------------------------------------------
__global__ __launch_bounds__(256) void lg_dot4(const float* __restrict__ ue,
                       const float* __restrict__ ie,
                       const float* __restrict__ x1,
                       const float* __restrict__ x2,
                       const float* __restrict__ x3,
                       const int*   __restrict__ uidx,
                       const int*   __restrict__ iidx,
                       float*       __restrict__ out,
                       int batch) {
    int bb   = blockIdx.x * 4 + (threadIdx.x >> 6);
    int lane = threadIdx.x & 63;
    if (bb >= batch) return;
    int u = uidx[bb];
    int i = iidx[bb];
    int t = NUM_USERS + i;
    int uo = (u << 6) + lane;
    int to = (t << 6) + lane;
    float au = ue[(u << 6) + lane] + x1[uo] + x2[uo] + x3[uo];
    float at = ie[(i << 6) + lane] + x1[to] + x2[to] + x3[to];
    float p  = au * at * (1.0f / 16.0f);
    #pragma unroll
    for (int off = 32; off > 0; off >>= 1)
        p += __shfl_down(p, off, 64);
    if (lane == 0) out[bb] = p;
}

// ---------------------------------------------------------------------------
extern "C" void kernel_launch(void* const* d_in, const int* in_sizes, int n_in,
                              void* d_out, int out_size, void* d_ws, size_t ws_size,
                              hipStream_t stream) {
    const float* user_emb  = (const float*)d_in[0];
    const float* item_emb  = (const float*)d_in[1];
    const int*   edge_rows = (const int*)  d_in[2];
    const int*   edge_cols = (const int*)  d_in[3];
    const float* edge_vals = (const float*)d_in[4];
    const int*   user_inp  = (const int*)  d_in[5];
    const int*   item_inp  = (const int*)  d_in[6];
    float*       out       = (float*)d_out;

    const int nnz = in_sizes[2];

    const size_t embBytes = (size_t)N_NODES * DIM * sizeof(float);  // 38.4 MB
    const size_t nodeInts = (size_t)N_NODES * sizeof(int);          // 600 KB
    const size_t need = 3 * embBytes + (size_t)nnz * 8 + 3 * nodeInts
                      + (size_t)(NPART + NBUCK) * sizeof(int);
    if (ws_size < need) return;  // workspace too small: fail clean (no OOB writes)

    char* ws = (char*)d_ws;
    float* x1    = (float*)(ws);
    float* x2    = (float*)(ws + embBytes);
    float* x3    = (float*)(ws + 2 * embBytes);
    int2*  edges = (int2*) (ws + 3 * embBytes);
    int*   cnt   = (int*)  (ws + 3 * embBytes + (size_t)nnz * 8);
    int*   ptr   = (int*)  (ws + 3 * embBytes + (size_t)nnz * 8 + nodeInts);
    int*   cur   = (int*)  (ws + 3 * embBytes + (size_t)nnz * 8 + 2 * nodeInts);
    int*   part  = (int*)  (ws + 3 * embBytes + (size_t)nnz * 8 + 3 * nodeInts);
    int*   bcur  = part + NPART;
    // bucket staging reuses x1 (28.8 MB <= 38.4 MB; consumed before SpMM 1)
    int*   brow  = (int*)x1;
    int2*  bcv   = (int2*)((char*)x1 + (size_t)nnz * 4);

    // --- CSR build (once; shared by all 3 layers) ---
    hipMemsetAsync(cnt, 0, nodeInts, stream);
    const int eb = (nnz + 255) / 256;
    lg_hist <<<eb,    256, 0, stream>>>(edge_rows, cnt, nnz);
    lg_scan1<<<NPART, 256, 0, stream>>>(cnt, ptr, part);
    lg_scan2<<<1,      64, 0, stream>>>(part, NPART);
    lg_scan3<<<NPART, 256, 0, stream>>>(ptr, part, cur);
    lg_bcur <<<1,      64, 0, stream>>>(ptr, bcur);
    lg_bucket<<<eb,   256, 0, stream>>>(edge_rows, edge_cols, edge_vals,
                                        bcur, brow, bcv, nnz);
    const int sgrid = (nnz / NBUCK + nnz / 64 + 255) / 256;  // bucket max + 18-sigma
    for (int b = 0; b < NBUCK; ++b)
        lg_scatter2<<<sgrid, 256, 0, stream>>>(brow, bcv, ptr, cur, edges, b, nnz);

    // --- 3 propagation layers (no acc; layer 1 reads emb inputs directly) ---
    const int rowBlocks = (N_NODES + 3) / 4;   // 4 waves (rows) per 256-thr block
    const float* xi_shift = item_emb - (size_t)NUM_USERS * DIM;  // never deref'd OOB
    lg_spmm<<<rowBlocks, 256, 0, stream>>>(ptr, cnt, edges, user_emb, xi_shift, x1);
    lg_spmm<<<rowBlocks, 256, 0, stream>>>(ptr, cnt, edges, x1, x1, x2);
    lg_spmm<<<rowBlocks, 256, 0, stream>>>(ptr, cnt, edges, x2, x2, x3);

    // --- final batched dot (acc formed in-register from 4 contributions) ---
    lg_dot4<<<(BATCH_N + 3) / 4, 256, 0, stream>>>(user_emb, item_emb, x1, x2, x3,
                                                   user_inp, item_inp, out, BATCH_N);
}

// Round 8
// 617.576 us; speedup vs baseline: 1.1993x; 1.1993x over previous
//
#include <hip/hip_runtime.h>

#define NUM_USERS 100000
#define NUM_ITEMS 50000
#define N_NODES   150000   // NUM_USERS + NUM_ITEMS
#define DIM       64
#define BATCH_N   16384
#define NPART     586      // ceil(N_NODES/256)
#define SC_PASSES 8        // scatter row-slice passes (2.4 MB dest window each,
#define SC_SLICE  18750    //  fits per-XCD 4 MB L2 -> no write amplification)

// ---------------------------------------------------------------------------
// CSR build step 1: histogram of edge rows (int atomics, cnt is L2-resident)
// ---------------------------------------------------------------------------
__global__ __launch_bounds__(256) void lg_hist(const int* __restrict__ rows,
                                               int* __restrict__ cnt, int nnz) {
    int e = blockIdx.x * blockDim.x + threadIdx.x;
    if (e < nnz) atomicAdd(&cnt[rows[e]], 1);
}

// CSR build step 2a: per-block (256-elem) exclusive scan; block totals to part[]
__global__ __launch_bounds__(256) void lg_scan1(const int* __restrict__ cnt,
                                                int* __restrict__ ptr,
                                                int* __restrict__ part) {
    __shared__ int s[256];
    int i = blockIdx.x * 256 + threadIdx.x;
    int v = (i < N_NODES) ? cnt[i] : 0;
    s[threadIdx.x] = v;
    __syncthreads();
    #pragma unroll
    for (int off = 1; off < 256; off <<= 1) {
        int t = (threadIdx.x >= off) ? s[threadIdx.x - off] : 0;
        __syncthreads();
        s[threadIdx.x] += t;
        __syncthreads();
    }
    if (i < N_NODES) ptr[i] = s[threadIdx.x] - v;   // exclusive within block
    if (threadIdx.x == 255) part[blockIdx.x] = s[255];
}

// CSR build step 2b: single-wave exclusive scan of the 586 block totals
__global__ __launch_bounds__(64) void lg_scan2(int* __restrict__ part, int n) {
    int lane = threadIdx.x & 63;
    int run = 0;
    for (int base = 0; base < n; base += 64) {
        int i = base + lane;
        int v = (i < n) ? part[i] : 0;
        int orig = v;
        #pragma unroll
        for (int off = 1; off < 64; off <<= 1) {
            int t = __shfl_up(v, off, 64);
            if (lane >= off) v += t;
        }
        if (i < n) part[i] = run + v - orig;        // exclusive
        run += __shfl(v, 63, 64);
    }
}

// CSR build step 2c: add block offsets; also init cursor = row start
__global__ __launch_bounds__(256) void lg_scan3(int* __restrict__ ptr,
                                                const int* __restrict__ part,
                                                int* __restrict__ cur) {
    int i = blockIdx.x * 256 + threadIdx.x;
    if (i < N_NODES) {
        int p = ptr[i] + part[blockIdx.x];
        ptr[i] = p;
        cur[i] = p;
    }
}

// ---------------------------------------------------------------------------
// CSR build step 3: scatter edges into CSR order as interleaved (col,val).
// Row-sliced into SC_PASSES sequential passes: each pass's destination window
// is a contiguous ~2.4 MB CSR range -> per-XCD-L2-resident RMWs, each dirty
// line written back once. (Measured round 6: fixes the 149 MB write-amp of
// the single-pass scatter; measured round 7: the LDS-aggregated bucket
// alternative is 6x WORSE due to same-address LDS atomic serialization.)
// ---------------------------------------------------------------------------
__global__ __launch_bounds__(256) void lg_scatter_pass(const int* __restrict__ rows,
                           const int* __restrict__ cols,
                           const float* __restrict__ vals, int* __restrict__ cur,
                           int2* __restrict__ edges, int nnz, int lo, int hi) {
    int e = blockIdx.x * blockDim.x + threadIdx.x;
    if (e >= nnz) return;
    int r = rows[e];
    if (r < lo || r >= hi) return;     // 7/8 of lanes exit: cheap row-slice filter
    int pos = atomicAdd(&cur[r], 1);
    edges[pos] = make_int2(cols[e], __float_as_int(vals[e]));
}

// ---------------------------------------------------------------------------
// Row-parallel SpMM: one wave per row, lane = dim. No atomics, no shuffles.
// Edge meta (col,val) is a wave-uniform 8B broadcast load (SGPR-based after
// readfirstlane). Per edge: 1 uniform load + 1 coalesced 256B gather + 1 FMA.
// Layer 1 reads user_emb/item_emb directly via per-edge base select (xi is
// pre-offset by -NUM_USERS*DIM); layers 2/3 pass xu == xi (select is no-op).
// 8-deep main loop + 4/2/1 remainder tiers keep many gathers in flight
// (degree ~ Poisson(16): the serial tail otherwise dominates half the rows).
// ---------------------------------------------------------------------------
__global__ __launch_bounds__(256) void lg_spmm(const int* __restrict__ ptr,
                            const int* __restrict__ cnt,
                            const int2* __restrict__ edges,
                            const float* __restrict__ xu,
                            const float* __restrict__ xi,
                            float* __restrict__ yout) {
    int r    = blockIdx.x * 4 + (threadIdx.x >> 6);
    int lane = threadIdx.x & 63;
    if (r >= N_NODES) return;
    int start = __builtin_amdgcn_readfirstlane(ptr[r]);   // SGPR: scalar addressing
    int len   = __builtin_amdgcn_readfirstlane(cnt[r]);
    const int2* __restrict__ ep = edges + start;
    float s0 = 0.0f, s1 = 0.0f, s2 = 0.0f, s3 = 0.0f;
    int j = 0;
    for (; j + 8 <= len; j += 8) {
        int2 m0 = ep[j];     int2 m1 = ep[j + 1];
        int2 m2 = ep[j + 2]; int2 m3 = ep[j + 3];
        int2 m4 = ep[j + 4]; int2 m5 = ep[j + 5];
        int2 m6 = ep[j + 6]; int2 m7 = ep[j + 7];
        const float* b0 = (m0.x < NUM_USERS) ? xu : xi;
        const float* b1 = (m1.x < NUM_USERS) ? xu : xi;
        const float* b2 = (m2.x < NUM_USERS) ? xu : xi;
        const float* b3 = (m3.x < NUM_USERS) ? xu : xi;
        const float* b4 = (m4.x < NUM_USERS) ? xu : xi;
        const float* b5 = (m5.x < NUM_USERS) ? xu : xi;
        const float* b6 = (m6.x < NUM_USERS) ? xu : xi;
        const float* b7 = (m7.x < NUM_USERS) ? xu : xi;
        s0 += __int_as_float(m0.y) * b0[(m0.x << 6) + lane];
        s1 += __int_as_float(m1.y) * b1[(m1.x << 6) + lane];
        s2 += __int_as_float(m2.y) * b2[(m2.x << 6) + lane];
        s3 += __int_as_float(m3.y) * b3[(m3.x << 6) + lane];
        s0 += __int_as_float(m4.y) * b4[(m4.x << 6) + lane];
        s1 += __int_as_float(m5.y) * b5[(m5.x << 6) + lane];
        s2 += __int_as_float(m6.y) * b6[(m6.x << 6) + lane];
        s3 += __int_as_float(m7.y) * b7[(m7.x << 6) + lane];
    }
    if (j + 4 <= len) {
        int2 m0 = ep[j];     int2 m1 = ep[j + 1];
        int2 m2 = ep[j + 2]; int2 m3 = ep[j + 3];
        const float* b0 = (m0.x < NUM_USERS) ? xu : xi;
        const float* b1 = (m1.x < NUM_USERS) ? xu : xi;
        const float* b2 = (m2.x < NUM_USERS) ? xu : xi;
        const float* b3 = (m3.x < NUM_USERS) ? xu : xi;
        s0 += __int_as_float(m0.y) * b0[(m0.x << 6) + lane];
        s1 += __int_as_float(m1.y) * b1[(m1.x << 6) + lane];
        s2 += __int_as_float(m2.y) * b2[(m2.x << 6) + lane];
        s3 += __int_as_float(m3.y) * b3[(m3.x << 6) + lane];
        j += 4;
    }
    if (j + 2 <= len) {
        int2 m0 = ep[j];     int2 m1 = ep[j + 1];
        const float* b0 = (m0.x < NUM_USERS) ? xu : xi;
        const float* b1 = (m1.x < NUM_USERS) ? xu : xi;
        s0 += __int_as_float(m0.y) * b0[(m0.x << 6) + lane];
        s1 += __int_as_float(m1.y) * b1[(m1.x << 6) + lane];
        j += 2;
    }
    if (j < len) {
        int2 m = ep[j];
        const float* b = (m.x < NUM_USERS) ? xu : xi;
        s0 += __int_as_float(m.y) * b[(m.x << 6) + lane];
    }
    float sum = (s0 + s1) + (s2 + s3);
    yout[(r << 6) + lane] = sum;
}

// ---------------------------------------------------------------------------
// preds[b] = dot(acc[u], acc[t]) / 16 with acc formed in-register from the
// 4 contributions (emb + x1 + x2 + x3) — full acc array never materialized.
// ---------------------------------------------------------------------------
__global__ __launch_bounds__(256) void lg_dot4(const float* __restrict__ ue,
                       const float* __restrict__ ie,
                       const float* __restrict__ x1,
                       const float* __restrict__ x2,
                       const float* __restrict__ x3,
                       const int*   __restrict__ uidx,
                       const int*   __restrict__ iidx,
                       float*       __restrict__ out,
                       int batch) {
    int bb   = blockIdx.x * 4 + (threadIdx.x >> 6);
    int lane = threadIdx.x & 63;
    if (bb >= batch) return;
    int u = uidx[bb];
    int i = iidx[bb];
    int t = NUM_USERS + i;
    int uo = (u << 6) + lane;
    int to = (t << 6) + lane;
    float au = ue[(u << 6) + lane] + x1[uo] + x2[uo] + x3[uo];
    float at = ie[(i << 6) + lane] + x1[to] + x2[to] + x3[to];
    float p  = au * at * (1.0f / 16.0f);
    #pragma unroll
    for (int off = 32; off > 0; off >>= 1)
        p += __shfl_down(p, off, 64);
    if (lane == 0) out[bb] = p;
}

// ---------------------------------------------------------------------------
extern "C" void kernel_launch(void* const* d_in, const int* in_sizes, int n_in,
                              void* d_out, int out_size, void* d_ws, size_t ws_size,
                              hipStream_t stream) {
    const float* user_emb  = (const float*)d_in[0];
    const float* item_emb  = (const float*)d_in[1];
    const int*   edge_rows = (const int*)  d_in[2];
    const int*   edge_cols = (const int*)  d_in[3];
    const float* edge_vals = (const float*)d_in[4];
    const int*   user_inp  = (const int*)  d_in[5];
    const int*   item_inp  = (const int*)  d_in[6];
    float*       out       = (float*)d_out;

    const int nnz = in_sizes[2];

    const size_t embBytes = (size_t)N_NODES * DIM * sizeof(float);  // 38.4 MB
    const size_t nodeInts = (size_t)N_NODES * sizeof(int);          // 600 KB
    const size_t need = 3 * embBytes + (size_t)nnz * 8 + 3 * nodeInts
                      + (size_t)NPART * sizeof(int);
    if (ws_size < need) return;  // workspace too small: fail clean (no OOB writes)

    char* ws = (char*)d_ws;
    float* x1    = (float*)(ws);
    float* x2    = (float*)(ws + embBytes);
    float* x3    = (float*)(ws + 2 * embBytes);
    int2*  edges = (int2*) (ws + 3 * embBytes);
    int*   cnt   = (int*)  (ws + 3 * embBytes + (size_t)nnz * 8);
    int*   ptr   = (int*)  (ws + 3 * embBytes + (size_t)nnz * 8 + nodeInts);
    int*   cur   = (int*)  (ws + 3 * embBytes + (size_t)nnz * 8 + 2 * nodeInts);
    int*   part  = (int*)  (ws + 3 * embBytes + (size_t)nnz * 8 + 3 * nodeInts);

    // --- CSR build (once; shared by all 3 layers) ---
    hipMemsetAsync(cnt, 0, nodeInts, stream);
    const int eb = (nnz + 255) / 256;
    lg_hist <<<eb,    256, 0, stream>>>(edge_rows, cnt, nnz);
    lg_scan1<<<NPART, 256, 0, stream>>>(cnt, ptr, part);
    lg_scan2<<<1,      64, 0, stream>>>(part, NPART);
    lg_scan3<<<NPART, 256, 0, stream>>>(ptr, part, cur);
    for (int p = 0; p < SC_PASSES; ++p)
        lg_scatter_pass<<<eb, 256, 0, stream>>>(edge_rows, edge_cols, edge_vals,
                                                cur, edges, nnz,
                                                p * SC_SLICE, (p + 1) * SC_SLICE);

    // --- 3 propagation layers (no acc; layer 1 reads emb inputs directly) ---
    const int rowBlocks = (N_NODES + 3) / 4;   // 4 waves (rows) per 256-thr block
    const float* xi_shift = item_emb - (size_t)NUM_USERS * DIM;  // never deref'd OOB
    lg_spmm<<<rowBlocks, 256, 0, stream>>>(ptr, cnt, edges, user_emb, xi_shift, x1);
    lg_spmm<<<rowBlocks, 256, 0, stream>>>(ptr, cnt, edges, x1, x1, x2);
    lg_spmm<<<rowBlocks, 256, 0, stream>>>(ptr, cnt, edges, x2, x2, x3);

    // --- final batched dot (acc formed in-register from 4 contributions) ---
    lg_dot4<<<(BATCH_N + 3) / 4, 256, 0, stream>>>(user_emb, item_emb, x1, x2, x3,
                                                   user_inp, item_inp, out, BATCH_N);
}